// Round 11
// baseline (558.737 us; speedup 1.0000x reference)
//
#include <hip/hip_runtime.h>

// ---------------------------------------------------------------------------
// FastSelfAttention on MI355X (gfx950), round 11.
// B=8, S=4096, D=1024, H=16, DH=64.
// R11: (1) +q folded into per-batch weights (W2 = diag(v)Wt + I) -> `extra`
// path gone; (2) out-GEMM rebuilt at 128x128 / 4 waves / 64 KiB dbuf LDS
// (2 blocks/CU, R9's proven loop); (3) k_pool at 512 blocks (2/CU).
// qk-GEMM schedule frozen at R10 (941 TF plateau).
// ---------------------------------------------------------------------------

typedef unsigned short u16;
typedef float f32x4 __attribute__((ext_vector_type(4)));
typedef short bf16x8 __attribute__((ext_vector_type(8)));

#define DEV __device__ __forceinline__

DEV u16 f2bf(float f) {
  union { float f; unsigned u; } c; c.f = f;
  return (u16)((c.u + 0x7FFFu + ((c.u >> 16) & 1u)) >> 16);
}
DEV float bf2f(u16 h) {
  union { unsigned u; float f; } c; c.u = ((unsigned)h) << 16;
  return c.f;
}
// monotonic float<->uint key (for atomicMax on float values incl. negatives)
DEV unsigned fkey(float f) {
  unsigned u = __float_as_uint(f);
  return u ^ (unsigned)(((int)u >> 31) | 0x80000000);
}
DEV float unkey(unsigned k) {
  unsigned u = (k & 0x80000000u) ? (k ^ 0x80000000u) : ~k;
  return __uint_as_float(u);
}

#define SBAR_ __builtin_amdgcn_s_barrier()

// --- f32 -> bf16 bulk convert ----------------------------------------------
__global__ __launch_bounds__(256) void k_cvt(const float* __restrict__ in,
                                             u16* __restrict__ out, int n4) {
  int i = blockIdx.x * 256 + threadIdx.x;
  const int stride = gridDim.x * 256;
  for (; i < n4; i += stride) {
    float4 v = reinterpret_cast<const float4*>(in)[i];
    ushort4 o;
    o.x = f2bf(v.x); o.y = f2bf(v.y); o.z = f2bf(v.z); o.w = f2bf(v.w);
    reinterpret_cast<ushort4*>(out)[i] = o;
  }
}

// --- W (K,N) f32 -> W^T (N,K) bf16, 3 weights in one launch (z selects) ----
__global__ __launch_bounds__(256) void k_transw(const float* __restrict__ Wq,
                                                const float* __restrict__ Wk,
                                                const float* __restrict__ Wt,
                                                u16* __restrict__ Wqkt,
                                                u16* __restrict__ Wtt) {
  __shared__ float tile[32][33];
  const int z = blockIdx.z;
  const float* W = (z == 0) ? Wq : (z == 1) ? Wk : Wt;
  u16* D = (z == 0) ? Wqkt : (z == 1) ? (Wqkt + 1024 * 1024) : Wtt;
  const int bn = blockIdx.x, bk = blockIdx.y;
  const int tx = threadIdx.x & 31, ty = threadIdx.x >> 5;
#pragma unroll
  for (int j = 0; j < 4; ++j)
    tile[ty + j * 8][tx] = W[(size_t)(bk * 32 + ty + j * 8) * 1024 + bn * 32 + tx];
  __syncthreads();
#pragma unroll
  for (int j = 0; j < 4; ++j)
    D[(size_t)(bn * 32 + ty + j * 8) * 1024 + bk * 32 + tx] = f2bf(tile[tx][ty + j * 8]);
}

// --- Wbt[b][n][k] = bf16( Wtt[n][k]*pkr*pqr/(sumk*sumq) + (k==n) ) ---------
__global__ __launch_bounds__(256) void k_wbt(const u16* __restrict__ Wtt,
                                             const float* __restrict__ pkr,
                                             const float* __restrict__ pqr,
                                             const float* __restrict__ sumk,
                                             const float* __restrict__ sumq,
                                             u16* __restrict__ Wbt) {
  const int i = blockIdx.x * 256 + threadIdx.x;  // 1048576 threads
  const int k0 = (i & 127) * 8;
  const int n  = (i >> 7) & 1023;
  const int b  = i >> 17;
  const int hh = k0 >> 6;  // head of k-dim (8 elems stay in one head; DH=64)
  const float inv = 1.0f / (sumk[b * 16 + hh] * sumq[b * 16 + hh]);
  bf16x8 wv = *reinterpret_cast<const bf16x8*>(&Wtt[n * 1024 + k0]);
  bf16x8 o;
#pragma unroll
  for (int j = 0; j < 8; ++j) {
    const float p = pkr[b * 1024 + k0 + j] * pqr[b * 1024 + k0 + j] * inv;
    const float ident = (k0 + j == n) ? 1.0f : 0.0f;  // +I folds `out += q`
    o[j] = (short)f2bf(bf2f((u16)wv[j]) * p + ident);
  }
  *reinterpret_cast<bf16x8*>(&Wbt[(size_t)b * 1048576 + (size_t)n * 1024 + k0]) = o;
}

// --- qk-GEMM: 256x256, m201 8-phase (R10, frozen), bf16 LDS-staged out -----
__global__ __launch_bounds__(512, 2) void k_gemm8(const u16* __restrict__ A,
                                                  const u16* __restrict__ Bt,
                                                  const float* __restrict__ bias0,
                                                  const float* __restrict__ bias1,
                                                  u16* __restrict__ C0,
                                                  u16* __restrict__ C1,
                                                  int gcols) {
  __shared__ __align__(16) u16 lds[2 * 32768];  // [buf][A|B][256][64]
  const int tid = threadIdx.x;
  const int w = tid >> 6, lane = tid & 63;
  const int wm = w >> 2, wn = w & 3;

  const int nwg = gridDim.x;
  const int swz = (blockIdx.x & 7) * (nwg >> 3) + (blockIdx.x >> 3);
  const int ci = swz % gcols, ri = swz / gcols;
  const int row0 = ri * 256, col0 = ci * 256;

  const int sr = tid >> 3;
  const int ls8 = ((tid & 7) ^ (sr & 7)) * 8;
  const u16* gA = A + (size_t)(row0 + sr) * 1024 + ls8;
  const u16* gB = Bt + (size_t)(col0 + sr) * 1024 + ls8;

  auto stage = [&](int buf, int mat, int half, int kt, const u16* g) {
#pragma unroll
    for (int p = 0; p < 2; ++p) {
      const u16* src = g + (size_t)(half * 128 + p * 64) * 1024 + kt;
      u16* dst = (u16*)&lds[buf * 32768 + mat * 16384 + half * 8192 + p * 4096 + w * 512];
      __builtin_amdgcn_global_load_lds(
          (const __attribute__((address_space(1))) void*)src,
          (__attribute__((address_space(3))) void*)dst, 16, 0, 0);
    }
  };

  f32x4 acc[8][4] = {};

  stage(0, 0, 0, 0, gA);
  stage(0, 0, 1, 0, gA);
  stage(0, 1, 0, 0, gB);
  stage(0, 1, 1, 0, gB);
  stage(1, 1, 0, 64, gB);
  stage(1, 1, 1, 64, gB);
  asm volatile("s_waitcnt vmcnt(4)" ::: "memory");
  SBAR_;

  const int lr15 = lane & 15, lhi = lane >> 4, lx = lane & 7;
  bf16x8 A0f[4][2], A1f[4][2], B0f[2][2], B1f[2][2];

#define RD_Ah(dst, base, half)                                                 \
  _Pragma("unroll") for (int mi = 0; mi < 4; ++mi)                             \
  _Pragma("unroll") for (int ks = 0; ks < 2; ++ks)                             \
    dst[mi][ks] = *reinterpret_cast<const bf16x8*>(                            \
        &(base)[(wm * 128 + (half) * 64 + mi * 16 + lr15) * 64 +               \
                (((ks << 2) | lhi) ^ lx) * 8]);
#define RD_Bh(dst, base, half)                                                 \
  _Pragma("unroll") for (int ni = 0; ni < 2; ++ni)                             \
  _Pragma("unroll") for (int ks = 0; ks < 2; ++ks)                             \
    dst[ni][ks] = *reinterpret_cast<const bf16x8*>(                            \
        &(base)[(wn * 64 + (half) * 32 + ni * 16 + lr15) * 64 +                \
                (((ks << 2) | lhi) ^ lx) * 8]);
#define MFMA_Q(ar, br, mo, no)                                                 \
  _Pragma("unroll") for (int mi = 0; mi < 4; ++mi)                             \
  _Pragma("unroll") for (int ni = 0; ni < 2; ++ni)                             \
  _Pragma("unroll") for (int ks = 0; ks < 2; ++ks)                             \
    acc[(mo) + mi][(no) + ni] = __builtin_amdgcn_mfma_f32_16x16x32_bf16(       \
        ar[mi][ks], br[ni][ks], acc[(mo) + mi][(no) + ni], 0, 0, 0);

#define LGKM0_ asm volatile("s_waitcnt lgkmcnt(0)" ::: "memory")
#define LGKM8_ asm volatile("s_waitcnt lgkmcnt(8)" ::: "memory")
#define PRIO1_ __builtin_amdgcn_s_setprio(1)
#define PRIO0_ __builtin_amdgcn_s_setprio(0)

  const u16* bA0 = &lds[0];
  const u16* bB0 = bA0 + 16384;
  const u16* bA1 = &lds[32768];
  const u16* bB1 = bA1 + 16384;

  for (int i = 0; i < 8; ++i) {
    const int t1k = (2 * i + 1) * 64;
    const int t2k = (2 * i + 2) * 64;
    const int t3k = (2 * i + 3) * 64;
    const bool pf = (i < 7);

    RD_Ah(A0f, bA0, 0);
    RD_Bh(B0f, bB0, 0);
    stage(1, 0, 0, t1k, gA);
    LGKM8_;
    SBAR_;
    LGKM0_;
    PRIO1_; MFMA_Q(A0f, B0f, 0, 0); PRIO0_;
    SBAR_;

    RD_Bh(B1f, bB0, 1);
    stage(1, 0, 1, t1k, gA);
    SBAR_;
    LGKM0_;
    PRIO1_; MFMA_Q(A0f, B1f, 0, 2); PRIO0_;
    SBAR_;

    RD_Ah(A1f, bA0, 1);
    if (pf) stage(0, 1, 0, t2k, gB);
    SBAR_;
    LGKM0_;
    PRIO1_; MFMA_Q(A1f, B1f, 4, 2); PRIO0_;
    SBAR_;

    if (pf) {
      stage(0, 1, 1, t2k, gB);
      asm volatile("s_waitcnt vmcnt(4)" ::: "memory");
    } else {
      asm volatile("s_waitcnt vmcnt(0)" ::: "memory");
    }
    SBAR_;
    PRIO1_; MFMA_Q(A1f, B0f, 4, 0); PRIO0_;
    SBAR_;

    RD_Ah(A0f, bA1, 0);
    RD_Bh(B0f, bB1, 0);
    if (pf) stage(0, 0, 0, t2k, gA);
    LGKM8_;
    SBAR_;
    LGKM0_;
    PRIO1_; MFMA_Q(A0f, B0f, 0, 0); PRIO0_;
    SBAR_;

    RD_Bh(B1f, bB1, 1);
    if (pf) stage(0, 0, 1, t2k, gA);
    SBAR_;
    LGKM0_;
    PRIO1_; MFMA_Q(A0f, B1f, 0, 2); PRIO0_;
    SBAR_;

    RD_Ah(A1f, bA1, 1);
    if (pf) stage(1, 1, 0, t3k, gB);
    SBAR_;
    LGKM0_;
    PRIO1_; MFMA_Q(A1f, B1f, 4, 2); PRIO0_;
    SBAR_;

    if (pf) {
      stage(1, 1, 1, t3k, gB);
      asm volatile("s_waitcnt vmcnt(4)" ::: "memory");
    }
    SBAR_;
    PRIO1_; MFMA_Q(A1f, B0f, 4, 0); PRIO0_;
    SBAR_;
  }

  // epilogue: bf16 LDS-staged coalesced store
  {
    u16* cl = (u16*)lds;
    const bool lo = (ci < (gcols >> 1));
    const float* bias = lo ? bias0 : bias1;
    u16* dst = lo ? C0 : C1;
    const int colloc0 = col0 - (lo ? 0 : 1024);
#pragma unroll
    for (int n = 0; n < 4; ++n) {
      const int cc = wn * 64 + n * 16 + lr15;
      const float bv = bias[colloc0 + cc];
#pragma unroll
      for (int m = 0; m < 8; ++m) {
        const int rb = wm * 128 + m * 16 + lhi * 4;
#pragma unroll
        for (int j = 0; j < 4; ++j) {
          const int r = rb + j;
          cl[r * 256 + (cc ^ ((r & 12) << 2))] = f2bf(acc[m][n][j] + bv);
        }
      }
    }
    __syncthreads();
#pragma unroll
    for (int pass = 0; pass < 16; ++pass) {
      const int idx = pass * 512 + tid;
      const int r = idx >> 5, g = idx & 31;
      bf16x8 v = *reinterpret_cast<const bf16x8*>(
          &cl[r * 256 + ((g * 8) ^ ((r & 12) << 2))]);
      *reinterpret_cast<bf16x8*>(
          &dst[(size_t)(row0 + r) * 1024 + colloc0 + g * 8]) = v;
    }
  }
#undef RD_Ah
#undef RD_Bh
#undef MFMA_Q
#undef LGKM0_
#undef LGKM8_
#undef PRIO1_
#undef PRIO0_
}

// --- out-GEMM: 128x128, 4 waves, 64 KiB dbuf LDS (2 blocks/CU) -------------
// Cf = A(Mx1024) @ W2_b(Nx1024)^T + bias.  W2 includes +I (out += q fold).
// R9's proven loop: reads+MFMA -> barrier -> stage t+2 -> vmcnt(8) -> barrier.
__global__ __launch_bounds__(256, 2) void k_gemm_out(const u16* __restrict__ A,
                                                     const u16* __restrict__ Bt,
                                                     const float* __restrict__ bias,
                                                     float* __restrict__ Cf) {
  __shared__ __align__(16) u16 lds[2 * 16384];  // [buf][A|B][128][64]
  const int tid = threadIdx.x;
  const int w = tid >> 6, lane = tid & 63;
  const int wm = w >> 1, wn = w & 1;

  // chunked XCD swizzle; nwg = 2048, gcols = 8 -> each XCD chunk = 1 batch
  const int nwg = gridDim.x;
  const int swz = (blockIdx.x & 7) * (nwg >> 3) + (blockIdx.x >> 3);
  const int ci = swz & 7, ri = swz >> 3;
  const int row0 = ri * 128, col0 = ci * 128;

  const int sr = tid >> 3;  // 0..31
  const int ls8 = ((tid & 7) ^ (sr & 7)) * 8;
  const u16* gA = A + (size_t)(row0 + sr) * 1024 + ls8;
  const u16* gB = Bt + (size_t)(row0 >> 12) * 1048576 +
                  (size_t)(col0 + sr) * 1024 + ls8;

  auto stage = [&](int buf, int mat, int kt, const u16* g) {
#pragma unroll
    for (int p = 0; p < 4; ++p) {
      const u16* src = g + (size_t)(p * 32) * 1024 + kt;
      u16* dst = (u16*)&lds[buf * 16384 + mat * 8192 + p * 2048 + tid * 8];
      __builtin_amdgcn_global_load_lds(
          (const __attribute__((address_space(1))) void*)src,
          (__attribute__((address_space(3))) void*)dst, 16, 0, 0);
    }
  };

  f32x4 acc[4][4] = {};

  // prologue: tile0 -> buf0 (8 loads), tile1 -> buf1 (8 loads)
  stage(0, 0, 0, gA);
  stage(0, 1, 0, gB);
  stage(1, 0, 64, gA);
  stage(1, 1, 64, gB);
  asm volatile("s_waitcnt vmcnt(8)" ::: "memory");  // tile0 landed
  SBAR_;

  const int lr15 = lane & 15, lhi = lane >> 4, lx = lane & 7;
  bf16x8 Af[4][2], Bf[4][2];

  int cur = 0;
  for (int t = 0; t < 16; ++t) {
    const u16* bA = &lds[cur * 16384];
    const u16* bB = bA + 8192;
    // reads (no fences -> compiler counted lgkm waits), then MFMAs
#pragma unroll
    for (int mi = 0; mi < 4; ++mi)
#pragma unroll
      for (int ks = 0; ks < 2; ++ks)
        Af[mi][ks] = *reinterpret_cast<const bf16x8*>(
            &bA[(wm * 64 + mi * 16 + lr15) * 64 + (((ks << 2) | lhi) ^ lx) * 8]);
#pragma unroll
    for (int ni = 0; ni < 4; ++ni)
#pragma unroll
      for (int ks = 0; ks < 2; ++ks)
        Bf[ni][ks] = *reinterpret_cast<const bf16x8*>(
            &bB[(wn * 64 + ni * 16 + lr15) * 64 + (((ks << 2) | lhi) ^ lx) * 8]);
    __builtin_amdgcn_s_setprio(1);
#pragma unroll
    for (int mi = 0; mi < 4; ++mi)
#pragma unroll
      for (int ni = 0; ni < 4; ++ni)
#pragma unroll
        for (int ks = 0; ks < 2; ++ks)
          acc[mi][ni] = __builtin_amdgcn_mfma_f32_16x16x32_bf16(
              Af[mi][ks], Bf[ni][ks], acc[mi][ni], 0, 0, 0);
    __builtin_amdgcn_s_setprio(0);
    SBAR_;  // all waves' reads of buf[cur] consumed
    if (t < 14) {
      stage(cur, 0, (t + 2) * 64, gA);
      stage(cur, 1, (t + 2) * 64, gB);
      asm volatile("s_waitcnt vmcnt(8)" ::: "memory");  // tile t+1 landed
    } else if (t == 14) {
      asm volatile("s_waitcnt vmcnt(0)" ::: "memory");
    }
    SBAR_;  // buf[cur^1] valid for all waves
    cur ^= 1;
  }

  // epilogue: f32 LDS-staged coalesced store (128x128 f32 = 64 KiB)
  {
    float* clf = (float*)lds;
#pragma unroll
    for (int n = 0; n < 4; ++n) {
      const int cc = wn * 64 + n * 16 + lr15;
#pragma unroll
      for (int m = 0; m < 4; ++m) {
        const int rb = wm * 64 + m * 16 + lhi * 4;
#pragma unroll
        for (int j = 0; j < 4; ++j) {
          const int r = rb + j;
          clf[r * 128 + (cc ^ ((r & 12) << 2))] = acc[m][n][j];
        }
      }
    }
    __syncthreads();
#pragma unroll
    for (int pass = 0; pass < 16; ++pass) {
      const int idx = pass * 256 + tid;
      const int r = idx >> 5, g = idx & 31;  // 128 rows x 32 groups of f32x4
      f32x4 v = *reinterpret_cast<const f32x4*>(
          &clf[r * 128 + ((g * 4) ^ ((r & 12) << 2))]);
      const int gcol = col0 + g * 4;
      float4 o;
      o.x = v[0] + bias[gcol + 0];
      o.y = v[1] + bias[gcol + 1];
      o.z = v[2] + bias[gcol + 2];
      o.w = v[3] + bias[gcol + 3];
      *reinterpret_cast<float4*>(&Cf[(size_t)(row0 + r) * 1024 + gcol]) = o;
    }
  }
}

// --- score[b,h,s] = (X.Weff[:,h] + bias[h])*scale + mask; + running max ----
template <int HAS_PQ>
__global__ __launch_bounds__(256) void k_score(const u16* __restrict__ X,
                                               const float* __restrict__ Wa,
                                               const float* __restrict__ bias,
                                               const float* __restrict__ mask,
                                               const float* __restrict__ pqr,
                                               const float* __restrict__ sumq,
                                               float* __restrict__ score,
                                               unsigned* __restrict__ maxkey,
                                               float scale) {
  __shared__ float waT[16][1024];  // [h][d]
  __shared__ unsigned bmx[4][16];
  __shared__ float invs[16];
  const int b = blockIdx.y;
  if (HAS_PQ && threadIdx.x < 16) invs[threadIdx.x] = 1.0f / sumq[b * 16 + threadIdx.x];
  if (HAS_PQ) __syncthreads();
  for (int t = threadIdx.x; t < 16384; t += 256) {
    const int d = t >> 4, h = t & 15;
    float wv = Wa[t];
    if (HAS_PQ) wv *= pqr[b * 1024 + d] * invs[d >> 6];
    waT[h][d] = wv;
  }
  __syncthreads();
  const int w = threadIdx.x >> 6, l = threadIdx.x & 63;
  float rm = -3.0e38f;
  for (int g = blockIdx.x * 4 + w; g < 1024; g += gridDim.x * 4) {
    const size_t r0 = (size_t)b * 4096 + g * 4;
    float cur[64];  // idx = rr*16 + h
#pragma unroll
    for (int i = 0; i < 64; ++i) cur[i] = 0.f;
    for (int i = 0; i < 8; ++i) {
      const int d = i * 128 + l * 2;
      float xv[4][2];
#pragma unroll
      for (int rr = 0; rr < 4; ++rr) {
        ushort2 xq = *reinterpret_cast<const ushort2*>(&X[(r0 + rr) * 1024 + d]);
        xv[rr][0] = bf2f(xq.x); xv[rr][1] = bf2f(xq.y);
      }
#pragma unroll
      for (int h = 0; h < 16; ++h) {
        float2 wv = *reinterpret_cast<const float2*>(&waT[h][d]);
#pragma unroll
        for (int rr = 0; rr < 4; ++rr)
          cur[rr * 16 + h] += xv[rr][0] * wv.x + xv[rr][1] * wv.y;
      }
    }
#pragma unroll
    for (int s = 0; s < 6; ++s) {
      const int m = 1 << s;
      const int bit = (l >> s) & 1;
#pragma unroll
      for (int j = 0; j < (32 >> s); ++j) {
        const float mine = bit ? cur[2 * j + 1] : cur[2 * j];
        const float other = bit ? cur[2 * j] : cur[2 * j + 1];
        cur[j] = mine + __shfl_xor(other, m, 64);
      }
    }
    const int rr = l >> 4, h = l & 15;
    const int si = g * 4 + rr;
    const float v = (cur[0] + bias[h]) * scale + mask[b * 4096 + si];
    score[((size_t)b * 16 + h) * 4096 + si] = v;
    rm = fmaxf(rm, v);
  }
  rm = fmaxf(rm, __shfl_xor(rm, 16, 64));
  rm = fmaxf(rm, __shfl_xor(rm, 32, 64));
  if (l < 16) bmx[w][l] = fkey(rm);
  __syncthreads();
  if (threadIdx.x < 16) {
    unsigned k = bmx[0][threadIdx.x];
    k = max(k, bmx[1][threadIdx.x]);
    k = max(k, bmx[2][threadIdx.x]);
    k = max(k, bmx[3][threadIdx.x]);
    atomicMax(&maxkey[b * 16 + threadIdx.x], k);
  }
}

// --- pool: w = exp(score-max); pooled[b,d] += sum_s w*X; sumexp[b,h] += w --
// 512 blocks (b x 8 chunks of 64 rows) -> 2 blocks/CU.
__global__ __launch_bounds__(256) void k_pool(const float* __restrict__ score,
                                              const unsigned* __restrict__ maxkey,
                                              const u16* __restrict__ X,
                                              float* __restrict__ pooled,
                                              float* __restrict__ sumexp) {
  __shared__ float wl[16][68];
  const int b = blockIdx.x >> 6, c = blockIdx.x & 63;
  const int s0 = c * 64;
  for (int t = threadIdx.x; t < 1024; t += 256) {
    const int h = t >> 6, si = t & 63;
    const float mx = unkey(maxkey[b * 16 + h]);
    wl[h][si] = __expf(score[((size_t)b * 16 + h) * 4096 + s0 + si] - mx);
  }
  __syncthreads();
  {
    const int h = threadIdx.x >> 4, part = threadIdx.x & 15;
    float s = 0.f;
#pragma unroll
    for (int j = 0; j < 4; ++j) s += wl[h][part * 4 + j];
#pragma unroll
    for (int m = 1; m < 16; m <<= 1) s += __shfl_xor(s, m, 64);
    if (part == 0) atomicAdd(&sumexp[b * 16 + h], s);
  }
  const int d0 = threadIdx.x * 4, h = threadIdx.x >> 4;
  float a0 = 0, a1 = 0, a2 = 0, a3 = 0;
#pragma unroll 4
  for (int si = 0; si < 64; ++si) {
    const float wv = wl[h][si];
    const size_t base = ((size_t)b * 4096 + s0 + si) * 1024 + d0;
    ushort4 xq = *reinterpret_cast<const ushort4*>(X + base);
    a0 += wv * bf2f(xq.x); a1 += wv * bf2f(xq.y);
    a2 += wv * bf2f(xq.z); a3 += wv * bf2f(xq.w);
  }
  atomicAdd(&pooled[b * 1024 + d0 + 0], a0);
  atomicAdd(&pooled[b * 1024 + d0 + 1], a1);
  atomicAdd(&pooled[b * 1024 + d0 + 2], a2);
  atomicAdd(&pooled[b * 1024 + d0 + 3], a3);
}

// ---------------------------------------------------------------------------
extern "C" void kernel_launch(void* const* d_in, const int* in_sizes, int n_in,
                              void* d_out, int out_size, void* d_ws, size_t ws_size,
                              hipStream_t stream) {
  (void)in_sizes; (void)n_in; (void)out_size; (void)ws_size;
  const float* x    = (const float*)d_in[0];
  const float* mask = (const float*)d_in[1];
  const float* Wq   = (const float*)d_in[2];
  const float* bq   = (const float*)d_in[3];
  const float* Wqa  = (const float*)d_in[4];
  const float* bqa  = (const float*)d_in[5];
  const float* Wk   = (const float*)d_in[6];
  const float* bk   = (const float*)d_in[7];
  const float* Wka  = (const float*)d_in[8];
  const float* bka  = (const float*)d_in[9];
  const float* Wt   = (const float*)d_in[10];
  const float* bt   = (const float*)d_in[11];
  float* out = (float*)d_out;
  char* ws = (char*)d_ws;

  size_t off = 0;
  auto take = [&](size_t b) { char* p = ws + off; off += (b + 255) & ~(size_t)255; return p; };
  u16*   xb    = (u16*)  take(67108864);   // x bf16
  u16*   qb    = (u16*)  take(67108864);   // q bf16
  u16*   kb    = (u16*)  take(67108864);   // k bf16
  u16*   Wqkt  = (u16*)  take(4194304);    // [Wq^T ; Wk^T] (2048 x 1024) bf16
  u16*   Wtt   = (u16*)  take(2097152);    // Wt^T bf16
  u16*   Wbt   = (u16*)  take(16777216);   // per-batch W2 = diag(v)Wt + I
  float* sc    = (float*)take(2097152);    // (B,H,S) scores
  char*  nb    = take(68608);
  float*    pqr  = (float*)nb;               // 32768 B
  float*    pkr  = (float*)(nb + 32768);     // 32768 B
  float*    sumq = (float*)(nb + 65536);     // 512 B
  float*    sumk = (float*)(nb + 66048);     // 512 B
  unsigned* maxq = (unsigned*)(nb + 66560);  // 512 B
  unsigned* maxk = (unsigned*)(nb + 67072);  // 512 B

  // prep
  k_cvt<<<2048, 256, 0, stream>>>(x, xb, 8388608);
  k_transw<<<dim3(32, 32, 3), 256, 0, stream>>>(Wq, Wk, Wt, Wqkt, Wtt);
  hipMemsetAsync(nb, 0, 68608, stream);

  // fused q,k = x @ [Wq|Wk] + [bq|bk]
  k_gemm8<<<1024, 512, 0, stream>>>(xb, Wqkt, bq, bk, qb, kb, 8);

  // q path: score (+max), pool (+sumexp)
  k_score<0><<<dim3(128, 8), 256, 0, stream>>>(qb, Wqa, bqa, mask, nullptr, nullptr,
                                               sc, maxq, 0.125f);
  k_pool<<<512, 256, 0, stream>>>(sc, maxq, qb, pqr, sumq);

  // k path (mixed_qk factored out; 1/sumq folded into Weff)
  k_score<1><<<dim3(128, 8), 256, 0, stream>>>(kb, Wka, bka, mask, pqr, sumq,
                                               sc, maxk, 0.125f);
  k_pool<<<512, 256, 0, stream>>>(sc, maxk, kb, pkr, sumk);

  // out = q @ W2_b + bt  (W2 = diag(pkr*pqr/(sumk*sumq))Wt + I)
  k_wbt<<<4096, 256, 0, stream>>>(Wtt, pkr, pqr, sumk, sumq, Wbt);
  k_gemm_out<<<2048, 256, 0, stream>>>(qb, Wbt, bt, out);
}

// Round 12
// 545.593 us; speedup vs baseline: 1.0241x; 1.0241x over previous
//
#include <hip/hip_runtime.h>

// ---------------------------------------------------------------------------
// FastSelfAttention on MI355X (gfx950), round 12.
// B=8, S=4096, D=1024, H=16, DH=64.
// R12: consolidation. R10 structure (best, 530us) + the two strictly-good
// R11 deltas: +I folded into W2 (out = q@W2+bt, no `extra` read path),
// f32 epilogue without extra. out-GEMM back to 256^2 8-phase template;
// k_pool back to 256 blocks. qk-GEMM frozen (941 TF plateau).
// ---------------------------------------------------------------------------

typedef unsigned short u16;
typedef float f32x4 __attribute__((ext_vector_type(4)));
typedef short bf16x8 __attribute__((ext_vector_type(8)));

#define DEV __device__ __forceinline__

DEV u16 f2bf(float f) {
  union { float f; unsigned u; } c; c.f = f;
  return (u16)((c.u + 0x7FFFu + ((c.u >> 16) & 1u)) >> 16);
}
DEV float bf2f(u16 h) {
  union { unsigned u; float f; } c; c.u = ((unsigned)h) << 16;
  return c.f;
}
DEV unsigned fkey(float f) {
  unsigned u = __float_as_uint(f);
  return u ^ (unsigned)(((int)u >> 31) | 0x80000000);
}
DEV float unkey(unsigned k) {
  unsigned u = (k & 0x80000000u) ? (k ^ 0x80000000u) : ~k;
  return __uint_as_float(u);
}

#define SBAR_ __builtin_amdgcn_s_barrier()

// --- f32 -> bf16 bulk convert ----------------------------------------------
__global__ __launch_bounds__(256) void k_cvt(const float* __restrict__ in,
                                             u16* __restrict__ out, int n4) {
  int i = blockIdx.x * 256 + threadIdx.x;
  const int stride = gridDim.x * 256;
  for (; i < n4; i += stride) {
    float4 v = reinterpret_cast<const float4*>(in)[i];
    ushort4 o;
    o.x = f2bf(v.x); o.y = f2bf(v.y); o.z = f2bf(v.z); o.w = f2bf(v.w);
    reinterpret_cast<ushort4*>(out)[i] = o;
  }
}

// --- W (K,N) f32 -> W^T (N,K) bf16, 3 weights in one launch (z selects) ----
__global__ __launch_bounds__(256) void k_transw(const float* __restrict__ Wq,
                                                const float* __restrict__ Wk,
                                                const float* __restrict__ Wt,
                                                u16* __restrict__ Wqkt,
                                                u16* __restrict__ Wtt) {
  __shared__ float tile[32][33];
  const int z = blockIdx.z;
  const float* W = (z == 0) ? Wq : (z == 1) ? Wk : Wt;
  u16* D = (z == 0) ? Wqkt : (z == 1) ? (Wqkt + 1024 * 1024) : Wtt;
  const int bn = blockIdx.x, bk = blockIdx.y;
  const int tx = threadIdx.x & 31, ty = threadIdx.x >> 5;
#pragma unroll
  for (int j = 0; j < 4; ++j)
    tile[ty + j * 8][tx] = W[(size_t)(bk * 32 + ty + j * 8) * 1024 + bn * 32 + tx];
  __syncthreads();
#pragma unroll
  for (int j = 0; j < 4; ++j)
    D[(size_t)(bn * 32 + ty + j * 8) * 1024 + bk * 32 + tx] = f2bf(tile[tx][ty + j * 8]);
}

// --- Wbt[b][n][k] = bf16( Wtt[n][k]*pkr*pqr/(sumk*sumq) + (k==n) ) ---------
__global__ __launch_bounds__(256) void k_wbt(const u16* __restrict__ Wtt,
                                             const float* __restrict__ pkr,
                                             const float* __restrict__ pqr,
                                             const float* __restrict__ sumk,
                                             const float* __restrict__ sumq,
                                             u16* __restrict__ Wbt) {
  const int i = blockIdx.x * 256 + threadIdx.x;  // 1048576 threads
  const int k0 = (i & 127) * 8;
  const int n  = (i >> 7) & 1023;
  const int b  = i >> 17;
  const int hh = k0 >> 6;
  const float inv = 1.0f / (sumk[b * 16 + hh] * sumq[b * 16 + hh]);
  bf16x8 wv = *reinterpret_cast<const bf16x8*>(&Wtt[n * 1024 + k0]);
  bf16x8 o;
#pragma unroll
  for (int j = 0; j < 8; ++j) {
    const float p = pkr[b * 1024 + k0 + j] * pqr[b * 1024 + k0 + j] * inv;
    const float ident = (k0 + j == n) ? 1.0f : 0.0f;  // +I folds `out += q`
    o[j] = (short)f2bf(bf2f((u16)wv[j]) * p + ident);
  }
  *reinterpret_cast<bf16x8*>(&Wbt[(size_t)b * 1048576 + (size_t)n * 1024 + k0]) = o;
}

// --- 256x256 GEMM, m201 8-phase template, LDS-staged epilogue --------------
// EPI 0: bf16 out split C0/C1 (qk fused GEMM).
// EPI 2: f32 out = acc + bias0[col] (out-GEMM; +q folded into Bt via +I);
//        Bt per-batch (Wbt + batch*1M), batch = row0>>12.
template <int EPI>
__global__ __launch_bounds__(512, 2) void k_gemm8(const u16* __restrict__ A,
                                                  const u16* __restrict__ Bt,
                                                  const float* __restrict__ bias0,
                                                  const float* __restrict__ bias1,
                                                  float* __restrict__ Cf,
                                                  u16* __restrict__ C0,
                                                  u16* __restrict__ C1,
                                                  int gcols) {
  __shared__ __align__(16) u16 lds[2 * 32768];  // [buf][A|B][256][64]
  const int tid = threadIdx.x;
  const int w = tid >> 6, lane = tid & 63;
  const int wm = w >> 2, wn = w & 3;

  const int nwg = gridDim.x;
  const int swz = (blockIdx.x & 7) * (nwg >> 3) + (blockIdx.x >> 3);
  const int ci = swz % gcols, ri = swz / gcols;
  const int row0 = ri * 256, col0 = ci * 256;

  const int sr = tid >> 3;
  const int ls8 = ((tid & 7) ^ (sr & 7)) * 8;
  const u16* gA = A + (size_t)(row0 + sr) * 1024 + ls8;
  const u16* gB;
  if (EPI == 2) {
    gB = Bt + (size_t)(row0 >> 12) * 1048576 + (size_t)(col0 + sr) * 1024 + ls8;
  } else {
    gB = Bt + (size_t)(col0 + sr) * 1024 + ls8;
  }

  auto stage = [&](int buf, int mat, int half, int kt, const u16* g) {
#pragma unroll
    for (int p = 0; p < 2; ++p) {
      const u16* src = g + (size_t)(half * 128 + p * 64) * 1024 + kt;
      u16* dst = (u16*)&lds[buf * 32768 + mat * 16384 + half * 8192 + p * 4096 + w * 512];
      __builtin_amdgcn_global_load_lds(
          (const __attribute__((address_space(1))) void*)src,
          (__attribute__((address_space(3))) void*)dst, 16, 0, 0);
    }
  };

  f32x4 acc[8][4] = {};

  stage(0, 0, 0, 0, gA);
  stage(0, 0, 1, 0, gA);
  stage(0, 1, 0, 0, gB);
  stage(0, 1, 1, 0, gB);
  stage(1, 1, 0, 64, gB);
  stage(1, 1, 1, 64, gB);
  asm volatile("s_waitcnt vmcnt(4)" ::: "memory");
  SBAR_;

  const int lr15 = lane & 15, lhi = lane >> 4, lx = lane & 7;
  bf16x8 A0f[4][2], A1f[4][2], B0f[2][2], B1f[2][2];

#define RD_Ah(dst, base, half)                                                 \
  _Pragma("unroll") for (int mi = 0; mi < 4; ++mi)                             \
  _Pragma("unroll") for (int ks = 0; ks < 2; ++ks)                             \
    dst[mi][ks] = *reinterpret_cast<const bf16x8*>(                            \
        &(base)[(wm * 128 + (half) * 64 + mi * 16 + lr15) * 64 +               \
                (((ks << 2) | lhi) ^ lx) * 8]);
#define RD_Bh(dst, base, half)                                                 \
  _Pragma("unroll") for (int ni = 0; ni < 2; ++ni)                             \
  _Pragma("unroll") for (int ks = 0; ks < 2; ++ks)                             \
    dst[ni][ks] = *reinterpret_cast<const bf16x8*>(                            \
        &(base)[(wn * 64 + (half) * 32 + ni * 16 + lr15) * 64 +                \
                (((ks << 2) | lhi) ^ lx) * 8]);
#define MFMA_Q(ar, br, mo, no)                                                 \
  _Pragma("unroll") for (int mi = 0; mi < 4; ++mi)                             \
  _Pragma("unroll") for (int ni = 0; ni < 2; ++ni)                             \
  _Pragma("unroll") for (int ks = 0; ks < 2; ++ks)                             \
    acc[(mo) + mi][(no) + ni] = __builtin_amdgcn_mfma_f32_16x16x32_bf16(       \
        ar[mi][ks], br[ni][ks], acc[(mo) + mi][(no) + ni], 0, 0, 0);

#define LGKM0_ asm volatile("s_waitcnt lgkmcnt(0)" ::: "memory")
#define LGKM8_ asm volatile("s_waitcnt lgkmcnt(8)" ::: "memory")
#define PRIO1_ __builtin_amdgcn_s_setprio(1)
#define PRIO0_ __builtin_amdgcn_s_setprio(0)

  const u16* bA0 = &lds[0];
  const u16* bB0 = bA0 + 16384;
  const u16* bA1 = &lds[32768];
  const u16* bB1 = bA1 + 16384;

  for (int i = 0; i < 8; ++i) {
    const int t1k = (2 * i + 1) * 64;
    const int t2k = (2 * i + 2) * 64;
    const int t3k = (2 * i + 3) * 64;
    const bool pf = (i < 7);

    RD_Ah(A0f, bA0, 0);
    RD_Bh(B0f, bB0, 0);
    stage(1, 0, 0, t1k, gA);
    LGKM8_;
    SBAR_;
    LGKM0_;
    PRIO1_; MFMA_Q(A0f, B0f, 0, 0); PRIO0_;
    SBAR_;

    RD_Bh(B1f, bB0, 1);
    stage(1, 0, 1, t1k, gA);
    SBAR_;
    LGKM0_;
    PRIO1_; MFMA_Q(A0f, B1f, 0, 2); PRIO0_;
    SBAR_;

    RD_Ah(A1f, bA0, 1);
    if (pf) stage(0, 1, 0, t2k, gB);
    SBAR_;
    LGKM0_;
    PRIO1_; MFMA_Q(A1f, B1f, 4, 2); PRIO0_;
    SBAR_;

    if (pf) {
      stage(0, 1, 1, t2k, gB);
      asm volatile("s_waitcnt vmcnt(4)" ::: "memory");
    } else {
      asm volatile("s_waitcnt vmcnt(0)" ::: "memory");
    }
    SBAR_;
    PRIO1_; MFMA_Q(A1f, B0f, 4, 0); PRIO0_;
    SBAR_;

    RD_Ah(A0f, bA1, 0);
    RD_Bh(B0f, bB1, 0);
    if (pf) stage(0, 0, 0, t2k, gA);
    LGKM8_;
    SBAR_;
    LGKM0_;
    PRIO1_; MFMA_Q(A0f, B0f, 0, 0); PRIO0_;
    SBAR_;

    RD_Bh(B1f, bB1, 1);
    if (pf) stage(0, 0, 1, t2k, gA);
    SBAR_;
    LGKM0_;
    PRIO1_; MFMA_Q(A0f, B1f, 0, 2); PRIO0_;
    SBAR_;

    RD_Ah(A1f, bA1, 1);
    if (pf) stage(1, 1, 0, t3k, gB);
    SBAR_;
    LGKM0_;
    PRIO1_; MFMA_Q(A1f, B1f, 4, 2); PRIO0_;
    SBAR_;

    if (pf) {
      stage(1, 1, 1, t3k, gB);
      asm volatile("s_waitcnt vmcnt(4)" ::: "memory");
    }
    SBAR_;
    PRIO1_; MFMA_Q(A1f, B0f, 4, 0); PRIO0_;
    SBAR_;
  }
#undef RD_Ah
#undef RD_Bh
#undef MFMA_Q
#undef LGKM0_
#undef LGKM8_
#undef PRIO1_
#undef PRIO0_

  // ---- epilogue: LDS-staged coalesced stores ----
  if constexpr (EPI == 0) {
    u16* cl = (u16*)lds;
    const bool lo = (ci < (gcols >> 1));
    const float* bias = lo ? bias0 : bias1;
    u16* dst = lo ? C0 : C1;
    const int colloc0 = col0 - (lo ? 0 : 1024);
#pragma unroll
    for (int n = 0; n < 4; ++n) {
      const int cc = wn * 64 + n * 16 + lr15;
      const float bv = bias[colloc0 + cc];
#pragma unroll
      for (int m = 0; m < 8; ++m) {
        const int rb = wm * 128 + m * 16 + lhi * 4;
#pragma unroll
        for (int j = 0; j < 4; ++j) {
          const int r = rb + j;
          cl[r * 256 + (cc ^ ((r & 12) << 2))] = f2bf(acc[m][n][j] + bv);
        }
      }
    }
    __syncthreads();
#pragma unroll
    for (int pass = 0; pass < 16; ++pass) {
      const int idx = pass * 512 + tid;
      const int r = idx >> 5, g = idx & 31;
      bf16x8 v = *reinterpret_cast<const bf16x8*>(
          &cl[r * 256 + ((g * 8) ^ ((r & 12) << 2))]);
      *reinterpret_cast<bf16x8*>(
          &dst[(size_t)(row0 + r) * 1024 + colloc0 + g * 8]) = v;
    }
  } else {
    float* clf = (float*)lds;
#pragma unroll
    for (int half = 0; half < 2; ++half) {
      __syncthreads();
      if (wm == half) {
#pragma unroll
        for (int n = 0; n < 4; ++n) {
          const int cc = wn * 64 + n * 16 + lr15;
#pragma unroll
          for (int m = 0; m < 8; ++m) {
            const int rb = m * 16 + lhi * 4;
#pragma unroll
            for (int j = 0; j < 4; ++j) {
              const int r = rb + j;
              clf[r * 256 + (cc ^ ((r & 12) << 2))] = acc[m][n][j];
            }
          }
        }
      }
      __syncthreads();
#pragma unroll
      for (int pass = 0; pass < 16; ++pass) {
        const int idx = pass * 512 + tid;
        const int r = idx >> 6, g = idx & 63;
        f32x4 v = *reinterpret_cast<const f32x4*>(
            &clf[r * 256 + ((g * 4) ^ ((r & 12) << 2))]);
        const int grow = row0 + half * 128 + r;
        const int gcol = col0 + g * 4;
        float4 o;
        o.x = v[0] + bias0[gcol + 0];
        o.y = v[1] + bias0[gcol + 1];
        o.z = v[2] + bias0[gcol + 2];
        o.w = v[3] + bias0[gcol + 3];
        *reinterpret_cast<float4*>(&Cf[(size_t)grow * 1024 + gcol]) = o;
      }
    }
  }
}

// --- score[b,h,s] = (X.Weff[:,h] + bias[h])*scale + mask; + running max ----
template <int HAS_PQ>
__global__ __launch_bounds__(256) void k_score(const u16* __restrict__ X,
                                               const float* __restrict__ Wa,
                                               const float* __restrict__ bias,
                                               const float* __restrict__ mask,
                                               const float* __restrict__ pqr,
                                               const float* __restrict__ sumq,
                                               float* __restrict__ score,
                                               unsigned* __restrict__ maxkey,
                                               float scale) {
  __shared__ float waT[16][1024];  // [h][d]
  __shared__ unsigned bmx[4][16];
  __shared__ float invs[16];
  const int b = blockIdx.y;
  if (HAS_PQ && threadIdx.x < 16) invs[threadIdx.x] = 1.0f / sumq[b * 16 + threadIdx.x];
  if (HAS_PQ) __syncthreads();
  for (int t = threadIdx.x; t < 16384; t += 256) {
    const int d = t >> 4, h = t & 15;
    float wv = Wa[t];
    if (HAS_PQ) wv *= pqr[b * 1024 + d] * invs[d >> 6];
    waT[h][d] = wv;
  }
  __syncthreads();
  const int w = threadIdx.x >> 6, l = threadIdx.x & 63;
  float rm = -3.0e38f;
  for (int g = blockIdx.x * 4 + w; g < 1024; g += gridDim.x * 4) {
    const size_t r0 = (size_t)b * 4096 + g * 4;
    float cur[64];  // idx = rr*16 + h
#pragma unroll
    for (int i = 0; i < 64; ++i) cur[i] = 0.f;
    for (int i = 0; i < 8; ++i) {
      const int d = i * 128 + l * 2;
      float xv[4][2];
#pragma unroll
      for (int rr = 0; rr < 4; ++rr) {
        ushort2 xq = *reinterpret_cast<const ushort2*>(&X[(r0 + rr) * 1024 + d]);
        xv[rr][0] = bf2f(xq.x); xv[rr][1] = bf2f(xq.y);
      }
#pragma unroll
      for (int h = 0; h < 16; ++h) {
        float2 wv = *reinterpret_cast<const float2*>(&waT[h][d]);
#pragma unroll
        for (int rr = 0; rr < 4; ++rr)
          cur[rr * 16 + h] += xv[rr][0] * wv.x + xv[rr][1] * wv.y;
      }
    }
#pragma unroll
    for (int s = 0; s < 6; ++s) {
      const int m = 1 << s;
      const int bit = (l >> s) & 1;
#pragma unroll
      for (int j = 0; j < (32 >> s); ++j) {
        const float mine = bit ? cur[2 * j + 1] : cur[2 * j];
        const float other = bit ? cur[2 * j] : cur[2 * j + 1];
        cur[j] = mine + __shfl_xor(other, m, 64);
      }
    }
    const int rr = l >> 4, h = l & 15;
    const int si = g * 4 + rr;
    const float v = (cur[0] + bias[h]) * scale + mask[b * 4096 + si];
    score[((size_t)b * 16 + h) * 4096 + si] = v;
    rm = fmaxf(rm, v);
  }
  rm = fmaxf(rm, __shfl_xor(rm, 16, 64));
  rm = fmaxf(rm, __shfl_xor(rm, 32, 64));
  if (l < 16) bmx[w][l] = fkey(rm);
  __syncthreads();
  if (threadIdx.x < 16) {
    unsigned k = bmx[0][threadIdx.x];
    k = max(k, bmx[1][threadIdx.x]);
    k = max(k, bmx[2][threadIdx.x]);
    k = max(k, bmx[3][threadIdx.x]);
    atomicMax(&maxkey[b * 16 + threadIdx.x], k);
  }
}

// --- pool: w = exp(score-max); pooled[b,d] += sum_s w*X; sumexp[b,h] += w --
__global__ __launch_bounds__(256) void k_pool(const float* __restrict__ score,
                                              const unsigned* __restrict__ maxkey,
                                              const u16* __restrict__ X,
                                              float* __restrict__ pooled,
                                              float* __restrict__ sumexp) {
  __shared__ float wl[16][132];
  const int b = blockIdx.x >> 5, c = blockIdx.x & 31;
  const int s0 = c * 128;
  for (int t = threadIdx.x; t < 2048; t += 256) {
    const int h = t >> 7, si = t & 127;
    const float mx = unkey(maxkey[b * 16 + h]);
    wl[h][si] = __expf(score[((size_t)b * 16 + h) * 4096 + s0 + si] - mx);
  }
  __syncthreads();
  {
    const int h = threadIdx.x >> 4, part = threadIdx.x & 15;
    float s = 0.f;
#pragma unroll
    for (int j = 0; j < 8; ++j) s += wl[h][part * 8 + j];
#pragma unroll
    for (int m = 1; m < 16; m <<= 1) s += __shfl_xor(s, m, 64);
    if (part == 0) atomicAdd(&sumexp[b * 16 + h], s);
  }
  const int d0 = threadIdx.x * 4, h = threadIdx.x >> 4;
  float a0 = 0, a1 = 0, a2 = 0, a3 = 0;
#pragma unroll 4
  for (int si = 0; si < 128; ++si) {
    const float wv = wl[h][si];
    const size_t base = ((size_t)b * 4096 + s0 + si) * 1024 + d0;
    ushort4 xq = *reinterpret_cast<const ushort4*>(X + base);
    a0 += wv * bf2f(xq.x); a1 += wv * bf2f(xq.y);
    a2 += wv * bf2f(xq.z); a3 += wv * bf2f(xq.w);
  }
  atomicAdd(&pooled[b * 1024 + d0 + 0], a0);
  atomicAdd(&pooled[b * 1024 + d0 + 1], a1);
  atomicAdd(&pooled[b * 1024 + d0 + 2], a2);
  atomicAdd(&pooled[b * 1024 + d0 + 3], a3);
}

// ---------------------------------------------------------------------------
extern "C" void kernel_launch(void* const* d_in, const int* in_sizes, int n_in,
                              void* d_out, int out_size, void* d_ws, size_t ws_size,
                              hipStream_t stream) {
  (void)in_sizes; (void)n_in; (void)out_size; (void)ws_size;
  const float* x    = (const float*)d_in[0];
  const float* mask = (const float*)d_in[1];
  const float* Wq   = (const float*)d_in[2];
  const float* bq   = (const float*)d_in[3];
  const float* Wqa  = (const float*)d_in[4];
  const float* bqa  = (const float*)d_in[5];
  const float* Wk   = (const float*)d_in[6];
  const float* bk   = (const float*)d_in[7];
  const float* Wka  = (const float*)d_in[8];
  const float* bka  = (const float*)d_in[9];
  const float* Wt   = (const float*)d_in[10];
  const float* bt   = (const float*)d_in[11];
  float* out = (float*)d_out;
  char* ws = (char*)d_ws;

  size_t off = 0;
  auto take = [&](size_t b) { char* p = ws + off; off += (b + 255) & ~(size_t)255; return p; };
  u16*   xb    = (u16*)  take(67108864);   // x bf16
  u16*   qb    = (u16*)  take(67108864);   // q bf16
  u16*   kb    = (u16*)  take(67108864);   // k bf16
  u16*   Wqkt  = (u16*)  take(4194304);    // [Wq^T ; Wk^T] (2048 x 1024) bf16
  u16*   Wtt   = (u16*)  take(2097152);    // Wt^T bf16
  u16*   Wbt   = (u16*)  take(16777216);   // per-batch W2 = diag(v)Wt + I
  float* sc    = (float*)take(2097152);    // (B,H,S) scores
  char*  nb    = take(68608);
  float*    pqr  = (float*)nb;               // 32768 B
  float*    pkr  = (float*)(nb + 32768);     // 32768 B
  float*    sumq = (float*)(nb + 65536);     // 512 B
  float*    sumk = (float*)(nb + 66048);     // 512 B
  unsigned* maxq = (unsigned*)(nb + 66560);  // 512 B
  unsigned* maxk = (unsigned*)(nb + 67072);  // 512 B

  // prep
  k_cvt<<<2048, 256, 0, stream>>>(x, xb, 8388608);
  k_transw<<<dim3(32, 32, 3), 256, 0, stream>>>(Wq, Wk, Wt, Wqkt, Wtt);
  hipMemsetAsync(nb, 0, 68608, stream);

  // fused q,k = x @ [Wq|Wk] + [bq|bk]
  k_gemm8<0><<<1024, 512, 0, stream>>>(xb, Wqkt, bq, bk, nullptr, qb, kb, 8);

  // q path: score (+max), pool (+sumexp)
  k_score<0><<<dim3(128, 8), 256, 0, stream>>>(qb, Wqa, bqa, mask, nullptr, nullptr,
                                               sc, maxq, 0.125f);
  k_pool<<<256, 256, 0, stream>>>(sc, maxq, qb, pqr, sumq);

  // k path (mixed_qk factored out; 1/sumq folded into Weff)
  k_score<1><<<dim3(128, 8), 256, 0, stream>>>(kb, Wka, bka, mask, pqr, sumq,
                                               sc, maxk, 0.125f);
  k_pool<<<256, 256, 0, stream>>>(sc, maxk, kb, pkr, sumk);

  // out = q @ W2_b + bt  (W2 = diag(pkr*pqr/(sumk*sumq))Wt + I)
  k_wbt<<<4096, 256, 0, stream>>>(Wtt, pkr, pqr, sumk, sumq, Wbt);
  k_gemm8<2><<<512, 512, 0, stream>>>(qb, Wbt, bt, nullptr, out, nullptr, nullptr, 4);
}